// Round 2
// baseline (697.977 us; speedup 1.0000x reference)
//
#include <hip/hip_runtime.h>

// PointPillars pseudo-image scatter, inverted to a single-pass gather.
// v6: TLP-first rewrite of the gather.
//     - single-buffered slab loop (#pragma unroll 1), 32 data VGPRs,
//       __launch_bounds__(256,8) -> target 8 waves/SIMD (was ~5).
//     - XCD-aware 1D-grid swizzle: bid%8 = XCD (HW round-robin), each XCD
//       owns 2 batches processed sequentially -> 3.07 MB feat slice stays
//       L2-resident (NT stores don't pollute L2).
// v5: slab fusion + prefetch pipeline (neutral -> ILP wasn't the lever).
// v4: two 4-cell groups per thread; all loads before all stores.
// v2: u16 per-batch voxel map (5.12 MB, memset 0xFF sentinel); nontemporal
//     coalesced 16 B stores for the 655 MB output (written exactly once).

constexpr int BATCH = 16;
constexpr int CH    = 64;
constexpr int NYD   = 400;
constexpr int NXD   = 400;
constexpr int NYNX  = NYD * NXD;   // 160000 cells per batch
constexpr int SLABS = 8;           // 8 channels per slab
constexpr int CPS   = CH / SLABS;  // 8
constexpr int TILE  = 1024;        // cells per block (256 thr * 4 cells)
constexpr int XB    = (NYNX + TILE - 1) / TILE;  // 157 x-blocks per batch
constexpr int NXCD  = 8;
constexpr int BPX   = BATCH / NXCD;              // 2 batches per XCD

typedef float f4 __attribute__((ext_vector_type(4)));

// Phase 1: map[b*NYNX + y*NX + x] = per-batch voxel id (i - b*nv), u16.
// map pre-filled with 0xFFFF via memsetAsync(0xFF).
__global__ void scatter_map_kernel(const int4* __restrict__ idx,
                                   unsigned short* __restrict__ map, int n, int nv) {
    int i = blockIdx.x * blockDim.x + threadIdx.x;
    if (i < n) {
        int4 v = idx[i];             // fields: b, z, y, x
        map[v.x * NYNX + v.z * NXD + v.w] = (unsigned short)(i - v.x * nv);
    }
}

// Phase 2: out[b, c, y, x] = live ? feat[(b*nv+j)*CH + c] : 0
// Thread owns 4 x-adjacent cells, loops over 8 channel slabs single-buffered.
__global__ __launch_bounds__(256, 8)
void gather_kernel(const float* __restrict__ feat,
                   const unsigned short* __restrict__ map,
                   float* __restrict__ out, int nv) {
    // XCD swizzle: consecutive block ids round-robin the 8 XCDs, so
    // xcd = bid & 7. Each XCD gets batches {2*xcd, 2*xcd+1}, sequentially.
    // Perf heuristic only -- correctness independent of the mapping.
    const int xcd = blockIdx.x & (NXCD - 1);
    const int idx = blockIdx.x >> 3;            // 0 .. 2*XB-1
    const int sub = (idx >= XB) ? 1 : 0;
    const int b   = xcd * BPX + sub;
    const int yx  = (idx - sub * XB) * TILE + threadIdx.x * 4;
    if (yx >= NYNX) return;   // no barriers below; early-exit is safe

    const unsigned short* mapb  = map  + (size_t)b * NYNX;
    const float*          featb = feat + ((size_t)b * nv) * CH;
    float*                outb  = out  + (size_t)b * CH * NYNX + yx;
    const f4 z4 = {0.f, 0.f, 0.f, 0.f};

    // one coalesced 8 B map load per thread, reused for all 8 slabs
    const ushort4 m = *reinterpret_cast<const ushort4*>(mapb + yx);
    bool live[4];
    int  off[4];                        // feat float-offset of cell's row
    {
        const unsigned short js[4] = {m.x, m.y, m.z, m.w};
        #pragma unroll
        for (int cc = 0; cc < 4; ++cc) {
            live[cc] = (js[cc] != 0xFFFFu);
            off[cc]  = (int)js[cc] * CH;
        }
    }

    // single-buffered slab loop: minimal live registers, latency hidden by
    // thread-level parallelism (8 waves/SIMD), not per-wave pipelining.
    #pragma unroll 1
    for (int s = 0; s < SLABS; ++s) {
        f4 f[4][2];
        #pragma unroll
        for (int cc = 0; cc < 4; ++cc) {
            if (live[cc]) {
                const f4* src = reinterpret_cast<const f4*>(featb + off[cc] + s * CPS);
                f[cc][0] = src[0];
                f[cc][1] = src[1];
            } else {
                f[cc][0] = z4;
                f[cc][1] = z4;
            }
        }

        // store slab s: 8 dense nontemporal 16 B stores (1024 B per wave-instr)
        float* outs = outb + (size_t)s * CPS * NYNX;
        #pragma unroll
        for (int k = 0; k < 2; ++k) {   // channels s*8+4k .. s*8+4k+3
            f4 r0 = {f[0][k].x, f[1][k].x, f[2][k].x, f[3][k].x};
            f4 r1 = {f[0][k].y, f[1][k].y, f[2][k].y, f[3][k].y};
            f4 r2 = {f[0][k].z, f[1][k].z, f[2][k].z, f[3][k].z};
            f4 r3 = {f[0][k].w, f[1][k].w, f[2][k].w, f[3][k].w};
            __builtin_nontemporal_store(r0, reinterpret_cast<f4*>(outs + (size_t)(4 * k + 0) * NYNX));
            __builtin_nontemporal_store(r1, reinterpret_cast<f4*>(outs + (size_t)(4 * k + 1) * NYNX));
            __builtin_nontemporal_store(r2, reinterpret_cast<f4*>(outs + (size_t)(4 * k + 2) * NYNX));
            __builtin_nontemporal_store(r3, reinterpret_cast<f4*>(outs + (size_t)(4 * k + 3) * NYNX));
        }
    }
}

// ---- Fallback path (only if d_ws is too small for the map) ----
__global__ void zero_kernel(float4* __restrict__ out, int n4) {
    int i = blockIdx.x * blockDim.x + threadIdx.x;
    if (i < n4) out[i] = make_float4(0.f, 0.f, 0.f, 0.f);
}

__global__ void direct_scatter_kernel(const float* __restrict__ feat,
                                      const int4* __restrict__ idx,
                                      float* __restrict__ out, int n) {
    int i = blockIdx.x * (blockDim.x / CH) + threadIdx.x / CH;
    int c = threadIdx.x % CH;
    if (i < n) {
        int4 v = idx[i];
        out[(size_t)(v.x * CH + c) * NYNX + v.z * NXD + v.w] = feat[(size_t)i * CH + c];
    }
}

extern "C" void kernel_launch(void* const* d_in, const int* in_sizes, int n_in,
                              void* d_out, int out_size, void* d_ws, size_t ws_size,
                              hipStream_t stream) {
    const float* feat = (const float*)d_in[0];
    const int4*  idx  = (const int4*)d_in[1];
    float*       out  = (float*)d_out;
    const int n  = in_sizes[1] / 4;          // number of pillars (192000)
    const int nv = n / BATCH;                // pillars per batch (12000)

    const size_t map_bytes = (size_t)BATCH * NYNX * sizeof(unsigned short);  // 5.12 MB
    if (ws_size >= map_bytes && nv < 0xFFFF) {
        unsigned short* map = (unsigned short*)d_ws;
        (void)hipMemsetAsync(map, 0xFF, map_bytes, stream);       // 0xFFFF fill
        scatter_map_kernel<<<(n + 255) / 256, 256, 0, stream>>>(idx, map, n, nv);
        gather_kernel<<<dim3(XB * BATCH), 256, 0, stream>>>(feat, map, out, nv);
    } else {
        int n4 = out_size / 4;
        zero_kernel<<<(n4 + 255) / 256, 256, 0, stream>>>((float4*)out, n4);
        direct_scatter_kernel<<<(n + 3) / 4, 256, 0, stream>>>(feat, idx, out, n);
    }
}

// Round 3
// 682.451 us; speedup vs baseline: 1.0228x; 1.0228x over previous
//
#include <hip/hip_runtime.h>

// PointPillars pseudo-image scatter, inverted to a single-pass gather.
// v7: exact v4 structure (the best-measured 670.7 us variant), ONE variable
//     changed: nontemporal stores -> plain stores. NT (no-allocate) was the
//     single untested invariant across v2-v6; plain stores let L2 aggregate
//     the 1 KB wave-bursts into larger, address-sorted DRAM evictions (the
//     6.2 TB/s harness fill uses plain stores).
// v6: occupancy/XCD-swizzle rewrite (null). v5: slab fusion (null).
// v4: two 4-cell groups per thread; all loads before all stores.
// v2: u16 per-batch voxel map (5.12 MB, memset 0xFF sentinel).

constexpr int BATCH = 16;
constexpr int CH    = 64;
constexpr int NYD   = 400;
constexpr int NXD   = 400;
constexpr int NYNX  = NYD * NXD;   // 160000 cells per batch
constexpr int SLABS = 8;           // 8 channels per slab
constexpr int CPS   = CH / SLABS;  // 8
constexpr int TILE  = 2048;        // cells per block (256 thr * 4 cells * 2 groups)

typedef float f4 __attribute__((ext_vector_type(4)));

// Phase 1: map[b*NYNX + y*NX + x] = per-batch voxel id (i - b*nv), u16.
// map pre-filled with 0xFFFF via memsetAsync(0xFF).
__global__ void scatter_map_kernel(const int4* __restrict__ idx,
                                   unsigned short* __restrict__ map, int n, int nv) {
    int i = blockIdx.x * blockDim.x + threadIdx.x;
    if (i < n) {
        int4 v = idx[i];             // fields: b, z, y, x
        map[v.x * NYNX + v.z * NXD + v.w] = (unsigned short)(i - v.x * nv);
    }
}

// Phase 2: out[b, c, y, x] = live ? feat[(b*nv+j)*CH + c] : 0
// Thread owns 2 groups of 4 x-adjacent cells (1024 apart) and 8 channels.
__global__ __launch_bounds__(256)
void gather_kernel(const float* __restrict__ feat,
                   const unsigned short* __restrict__ map,
                   float* __restrict__ out, int nv) {
    const int b    = blockIdx.y;
    const int c0   = blockIdx.z * CPS;
    const int base = blockIdx.x * TILE + threadIdx.x * 4;

    const unsigned short* mapb  = map + (size_t)b * NYNX;
    const float*          featb = feat + ((size_t)b * nv) * CH + c0;
    float*                outb  = out + ((size_t)b * CH + c0) * NYNX;
    const f4 z4 = {0.f, 0.f, 0.f, 0.f};

    // ---- load phase (no stores issued yet) ----
    bool gv[2];
    unsigned short js[2][4];
    f4 f[2][4][2];
    #pragma unroll
    for (int g = 0; g < 2; ++g) {
        const int yx = base + g * 1024;
        gv[g] = (yx < NYNX);
        ushort4 m = gv[g] ? *reinterpret_cast<const ushort4*>(mapb + yx)
                          : make_ushort4(0xFFFFu, 0xFFFFu, 0xFFFFu, 0xFFFFu);
        js[g][0] = m.x; js[g][1] = m.y; js[g][2] = m.z; js[g][3] = m.w;
        #pragma unroll
        for (int cc = 0; cc < 4; ++cc) {
            if (js[g][cc] != 0xFFFFu) {
                const f4* src = reinterpret_cast<const f4*>(featb + (size_t)js[g][cc] * CH);
                f[g][cc][0] = src[0];
                f[g][cc][1] = src[1];
            } else {
                f[g][cc][0] = z4;
                f[g][cc][1] = z4;
            }
        }
    }

    // ---- store phase: 16 dense plain 16 B stores (L2 write-combined) ----
    #pragma unroll
    for (int g = 0; g < 2; ++g) {
        if (!gv[g]) continue;
        const int yx = base + g * 1024;
        #pragma unroll
        for (int k = 0; k < 2; ++k) {   // channels c0+4k .. c0+4k+3
            f4 r0 = {f[g][0][k].x, f[g][1][k].x, f[g][2][k].x, f[g][3][k].x};
            f4 r1 = {f[g][0][k].y, f[g][1][k].y, f[g][2][k].y, f[g][3][k].y};
            f4 r2 = {f[g][0][k].z, f[g][1][k].z, f[g][2][k].z, f[g][3][k].z};
            f4 r3 = {f[g][0][k].w, f[g][1][k].w, f[g][2][k].w, f[g][3][k].w};
            *reinterpret_cast<f4*>(outb + (size_t)(4 * k + 0) * NYNX + yx) = r0;
            *reinterpret_cast<f4*>(outb + (size_t)(4 * k + 1) * NYNX + yx) = r1;
            *reinterpret_cast<f4*>(outb + (size_t)(4 * k + 2) * NYNX + yx) = r2;
            *reinterpret_cast<f4*>(outb + (size_t)(4 * k + 3) * NYNX + yx) = r3;
        }
    }
}

// ---- Fallback path (only if d_ws is too small for the map) ----
__global__ void zero_kernel(float4* __restrict__ out, int n4) {
    int i = blockIdx.x * blockDim.x + threadIdx.x;
    if (i < n4) out[i] = make_float4(0.f, 0.f, 0.f, 0.f);
}

__global__ void direct_scatter_kernel(const float* __restrict__ feat,
                                      const int4* __restrict__ idx,
                                      float* __restrict__ out, int n) {
    int i = blockIdx.x * (blockDim.x / CH) + threadIdx.x / CH;
    int c = threadIdx.x % CH;
    if (i < n) {
        int4 v = idx[i];
        out[(size_t)(v.x * CH + c) * NYNX + v.z * NXD + v.w] = feat[(size_t)i * CH + c];
    }
}

extern "C" void kernel_launch(void* const* d_in, const int* in_sizes, int n_in,
                              void* d_out, int out_size, void* d_ws, size_t ws_size,
                              hipStream_t stream) {
    const float* feat = (const float*)d_in[0];
    const int4*  idx  = (const int4*)d_in[1];
    float*       out  = (float*)d_out;
    const int n  = in_sizes[1] / 4;          // number of pillars (192000)
    const int nv = n / BATCH;                // pillars per batch (12000)

    const size_t map_bytes = (size_t)BATCH * NYNX * sizeof(unsigned short);  // 5.12 MB
    if (ws_size >= map_bytes && nv < 0xFFFF) {
        unsigned short* map = (unsigned short*)d_ws;
        (void)hipMemsetAsync(map, 0xFF, map_bytes, stream);       // 0xFFFF fill
        scatter_map_kernel<<<(n + 255) / 256, 256, 0, stream>>>(idx, map, n, nv);
        dim3 grid((NYNX + TILE - 1) / TILE, BATCH, SLABS);        // (79, 16, 8)
        gather_kernel<<<grid, 256, 0, stream>>>(feat, map, out, nv);
    } else {
        int n4 = out_size / 4;
        zero_kernel<<<(n4 + 255) / 256, 256, 0, stream>>>((float4*)out, n4);
        direct_scatter_kernel<<<(n + 3) / 4, 256, 0, stream>>>(feat, idx, out, n);
    }
}